// Round 1
// baseline (221.785 us; speedup 1.0000x reference)
//
#include <hip/hip_runtime.h>
#include <hip/hip_bf16.h>

// Problem constants
// B=16, L=50, D=8, H=128, E=128, NC=1000, NI=8192
#define NB 16
#define NL 50
#define ND 8
#define NH 128
#define NC 1000
#define NI 8192

// Output flat offsets (return order): catgy(16*8*1000), demand_score(16*50*8 flat),
// demand_score_candidate(16*8*8192), emb(800*128), emb_cand(8192*128), loss(1)
#define OFF_CAT  0
#define OFF_DS   128000
#define OFF_DSC  134400
#define OFF_EMB  1182976
#define OFF_EMBC 1285376
#define OFF_LOSS 2333952

// Workspace layout (floats)
#define WS_AGG  0         // 16*8*128   = 16384
#define WS_PD2  16384     // 16*8*128   = 16384
#define WS_PK   32768     // 800*128    = 102400
#define WS_PKCT 135168    // 128*8192   = 1048576 (transposed [h][i])

// ---------------------------------------------------------------------------
// K1a: session rows — gather emb (write out), hk = emb@Wk+bk, pk = hk@Wk1 -> ws
// 4 rows per block, 128 threads (thread = output column)
__global__ __launch_bounds__(128) void k_session(
    const int* __restrict__ inp, const float* __restrict__ emb_table,
    const float* __restrict__ Wk, const float* __restrict__ bk,
    const float* __restrict__ W1, float* __restrict__ out_emb,
    float* __restrict__ ws_pk)
{
    const int t = threadIdx.x;
    const int row0 = blockIdx.x * 4;
    __shared__ __align__(16) float e_s[4][128];
    __shared__ __align__(16) float h_s[4][128];
    #pragma unroll
    for (int r = 0; r < 4; ++r) {
        const int cat = inp[row0 + r];
        const float v = emb_table[cat * 128 + t];
        e_s[r][t] = v;
        out_emb[(row0 + r) * 128 + t] = v;
    }
    __syncthreads();
    const float bkv = bk[t];
    float acc[4] = {bkv, bkv, bkv, bkv};
    for (int k = 0; k < 128; k += 4) {
        const float w0 = Wk[(k + 0) * 128 + t], w1 = Wk[(k + 1) * 128 + t];
        const float w2 = Wk[(k + 2) * 128 + t], w3 = Wk[(k + 3) * 128 + t];
        #pragma unroll
        for (int r = 0; r < 4; ++r) {
            const float4 e4 = *reinterpret_cast<const float4*>(&e_s[r][k]);
            acc[r] = fmaf(e4.w, w3, fmaf(e4.z, w2, fmaf(e4.y, w1, fmaf(e4.x, w0, acc[r]))));
        }
    }
    #pragma unroll
    for (int r = 0; r < 4; ++r) h_s[r][t] = acc[r];
    __syncthreads();
    const float* __restrict__ Wk1 = W1 + 128 * 128;
    float pk[4] = {0.f, 0.f, 0.f, 0.f};
    for (int k = 0; k < 128; k += 4) {
        const float w0 = Wk1[(k + 0) * 128 + t], w1 = Wk1[(k + 1) * 128 + t];
        const float w2 = Wk1[(k + 2) * 128 + t], w3 = Wk1[(k + 3) * 128 + t];
        #pragma unroll
        for (int r = 0; r < 4; ++r) {
            const float4 h4 = *reinterpret_cast<const float4*>(&h_s[r][k]);
            pk[r] = fmaf(h4.w, w3, fmaf(h4.z, w2, fmaf(h4.y, w1, fmaf(h4.x, w0, pk[r]))));
        }
    }
    #pragma unroll
    for (int r = 0; r < 4; ++r) ws_pk[(row0 + r) * 128 + t] = pk[r];
}

// ---------------------------------------------------------------------------
// K1b: candidate rows — gather emb_cand (write out), hk=emb@Wk+bk, pkc=hk@Wk1
// stored TRANSPOSED [h][i]. 16 rows per block, 128 threads.
__global__ __launch_bounds__(128) void k_cand(
    const int* __restrict__ cand, const float* __restrict__ emb_table,
    const float* __restrict__ Wk, const float* __restrict__ bk,
    const float* __restrict__ W1, float* __restrict__ out_embc,
    float* __restrict__ ws_pkcT)
{
    const int t = threadIdx.x;
    const int i0 = blockIdx.x * 16;
    __shared__ __align__(16) float e_s[16][128];
    __shared__ __align__(16) float h_s[16][128];
    #pragma unroll
    for (int r = 0; r < 16; ++r) {
        const int cat = cand[i0 + r];
        const float v = emb_table[cat * 128 + t];
        e_s[r][t] = v;
        out_embc[(i0 + r) * 128 + t] = v;
    }
    __syncthreads();
    const float bkv = bk[t];
    float acc[16];
    #pragma unroll
    for (int r = 0; r < 16; ++r) acc[r] = bkv;
    for (int k = 0; k < 128; k += 4) {
        const float w0 = Wk[(k + 0) * 128 + t], w1 = Wk[(k + 1) * 128 + t];
        const float w2 = Wk[(k + 2) * 128 + t], w3 = Wk[(k + 3) * 128 + t];
        #pragma unroll
        for (int r = 0; r < 16; ++r) {
            const float4 e4 = *reinterpret_cast<const float4*>(&e_s[r][k]);
            acc[r] = fmaf(e4.w, w3, fmaf(e4.z, w2, fmaf(e4.y, w1, fmaf(e4.x, w0, acc[r]))));
        }
    }
    #pragma unroll
    for (int r = 0; r < 16; ++r) h_s[r][t] = acc[r];
    __syncthreads();
    const float* __restrict__ Wk1 = W1 + 128 * 128;
    #pragma unroll
    for (int r = 0; r < 16; ++r) acc[r] = 0.f;
    for (int k = 0; k < 128; k += 4) {
        const float w0 = Wk1[(k + 0) * 128 + t], w1 = Wk1[(k + 1) * 128 + t];
        const float w2 = Wk1[(k + 2) * 128 + t], w3 = Wk1[(k + 3) * 128 + t];
        #pragma unroll
        for (int r = 0; r < 16; ++r) {
            const float4 h4 = *reinterpret_cast<const float4*>(&h_s[r][k]);
            acc[r] = fmaf(h4.w, w3, fmaf(h4.z, w2, fmaf(h4.y, w1, fmaf(h4.x, w0, acc[r]))));
        }
    }
    // per-thread 16 consecutive i's -> 4x float4 stores (64B/lane, line-granular)
    float4* dst = reinterpret_cast<float4*>(&ws_pkcT[(size_t)t * NI + i0]);
    #pragma unroll
    for (int r4 = 0; r4 < 4; ++r4)
        dst[r4] = make_float4(acc[r4 * 4 + 0], acc[r4 * 4 + 1], acc[r4 * 4 + 2], acc[r4 * 4 + 3]);
}

// ---------------------------------------------------------------------------
// K2: agg[b,d,h] = logsumexp_l( emb[b,l,:] @ Wd[:, d*128+h] )
// block per (b,d); 256 threads = 2 halves of L (25 each) x 128 cols
__global__ __launch_bounds__(256) void k_agg(
    const float* __restrict__ out_emb, const float* __restrict__ Wd,
    float* __restrict__ ws_agg)
{
    const int bd = blockIdx.x;         // b*8+d
    const int b = bd >> 3, d = bd & 7;
    const int t = threadIdx.x;
    const int c = t & 127, half = t >> 7;
    __shared__ __align__(16) float e_s[NL * 128];
    __shared__ float m_s[2][128];
    __shared__ float s_s[2][128];
    for (int i = t; i < NL * 128; i += 256) e_s[i] = out_emb[b * NL * 128 + i];
    __syncthreads();
    const float* __restrict__ wp = Wd + d * 128 + c;
    float hd[25];
    #pragma unroll
    for (int l = 0; l < 25; ++l) hd[l] = 0.f;
    const int l0 = half * 25;
    for (int k = 0; k < 128; k += 4) {
        const float w0 = wp[(k + 0) * 1024], w1 = wp[(k + 1) * 1024];
        const float w2 = wp[(k + 2) * 1024], w3 = wp[(k + 3) * 1024];
        #pragma unroll
        for (int l = 0; l < 25; ++l) {
            const float4 e4 = *reinterpret_cast<const float4*>(&e_s[(l0 + l) * 128 + k]);
            hd[l] = fmaf(e4.w, w3, fmaf(e4.z, w2, fmaf(e4.y, w1, fmaf(e4.x, w0, hd[l]))));
        }
    }
    float m = hd[0];
    #pragma unroll
    for (int l = 1; l < 25; ++l) m = fmaxf(m, hd[l]);
    float s = 0.f;
    #pragma unroll
    for (int l = 0; l < 25; ++l) s += expf(hd[l] - m);
    m_s[half][c] = m; s_s[half][c] = s;
    __syncthreads();
    if (half == 0) {
        const float m0 = m_s[0][c], m1 = m_s[1][c];
        const float M = fmaxf(m0, m1);
        const float sv = s_s[0][c] * expf(m0 - M) + s_s[1][c] * expf(m1 - M);
        ws_agg[bd * 128 + c] = M + logf(sv);
    }
}

// ---------------------------------------------------------------------------
// K3: pd2[r][t] = agg[r]@Wd1 + b1  (b1 folded here, used by both score paths)
__global__ __launch_bounds__(128) void k_pd2(
    const float* __restrict__ ws_agg, const float* __restrict__ W1,
    const float* __restrict__ b1, float* __restrict__ ws_pd2)
{
    const int r = blockIdx.x;
    const int t = threadIdx.x;
    __shared__ __align__(16) float a_s[128];
    a_s[t] = ws_agg[r * 128 + t];
    __syncthreads();
    float acc = b1[t];
    for (int k = 0; k < 128; k += 4) {
        acc = fmaf(a_s[k + 0], W1[(k + 0) * 128 + t], acc);
        acc = fmaf(a_s[k + 1], W1[(k + 1) * 128 + t], acc);
        acc = fmaf(a_s[k + 2], W1[(k + 2) * 128 + t], acc);
        acc = fmaf(a_s[k + 3], W1[(k + 3) * 128 + t], acc);
    }
    ws_pd2[r * 128 + t] = acc;
}

// ---------------------------------------------------------------------------
// K4: demand_sim_loss (single block). loss_b = sum_h S_h^2 - sum_{d,h} hn^2
__global__ __launch_bounds__(128) void k_loss(
    const float* __restrict__ agg, float* __restrict__ out_loss)
{
    __shared__ float normp[2][8];
    __shared__ float redw[2];
    const int t = threadIdx.x;
    const int lane = t & 63, wid = t >> 6;
    float part = 0.f;
    for (int b = 0; b < NB; ++b) {
        float a[8];
        #pragma unroll
        for (int d = 0; d < 8; ++d) a[d] = agg[(b * 8 + d) * 128 + t];
        #pragma unroll
        for (int d = 0; d < 8; ++d) {
            float s = a[d] * a[d];
            s += __shfl_down(s, 32); s += __shfl_down(s, 16); s += __shfl_down(s, 8);
            s += __shfl_down(s, 4);  s += __shfl_down(s, 2);  s += __shfl_down(s, 1);
            if (lane == 0) normp[wid][d] = s;
        }
        __syncthreads();
        float S = 0.f, sq = 0.f;
        #pragma unroll
        for (int d = 0; d < 8; ++d) {
            const float nrm = sqrtf(normp[0][d] + normp[1][d]) + 1e-12f;
            const float hn = a[d] / nrm;
            S += hn;
            sq = fmaf(hn, hn, sq);
        }
        part += S * S - sq;
        __syncthreads();
    }
    part += __shfl_down(part, 32); part += __shfl_down(part, 16); part += __shfl_down(part, 8);
    part += __shfl_down(part, 4);  part += __shfl_down(part, 2);  part += __shfl_down(part, 1);
    if (lane == 0) redw[wid] = part;
    __syncthreads();
    if (t == 0) out_loss[0] = (redw[0] + redw[1]) * (1.0f / 896.0f);
}

// ---------------------------------------------------------------------------
// K5: catgy_score[r, col] = agg[r]@Wc[:,col] + bc[col], r = b*8+d (128 rows)
__global__ __launch_bounds__(128) void k_catgy(
    const float* __restrict__ ws_agg, const float* __restrict__ Wc,
    const float* __restrict__ bc, float* __restrict__ out_cat)
{
    const int r = blockIdx.x;
    const int cc = blockIdx.y;
    const int t = threadIdx.x;
    __shared__ __align__(16) float a_s[128];
    a_s[t] = ws_agg[r * 128 + t];
    __syncthreads();
    if (t < 125) {
        const int col = cc * 125 + t;
        float acc = bc[col];
        for (int k = 0; k < 128; k += 4) {
            acc = fmaf(a_s[k + 0], Wc[(k + 0) * NC + col], acc);
            acc = fmaf(a_s[k + 1], Wc[(k + 1) * NC + col], acc);
            acc = fmaf(a_s[k + 2], Wc[(k + 2) * NC + col], acc);
            acc = fmaf(a_s[k + 3], Wc[(k + 3) * NC + col], acc);
        }
        out_cat[r * NC + col] = acc;
    }
}

// ---------------------------------------------------------------------------
// K6: demand_score[b,l,d] = sum_h relu(pd2[b,d,h]+pk[b,l,h]) * w_score[h]
// Flat output index b*400 + l*8 + d (the (B,L,D)->(B,D,L) reshape is flat-identity)
__global__ __launch_bounds__(128) void k_demand_score(
    const float* __restrict__ ws_pd2, const float* __restrict__ ws_pk,
    const float* __restrict__ w_score, float* __restrict__ out_ds)
{
    const int bl = blockIdx.x;         // b*50+l
    const int b = bl / 50, l = bl % 50;
    const int t = threadIdx.x;
    __shared__ float red[2][8];
    const int lane = t & 63, wid = t >> 6;
    const float pkv = ws_pk[bl * 128 + t];
    const float wv = w_score[t];
    #pragma unroll
    for (int d = 0; d < 8; ++d) {
        float v = fmaxf(ws_pd2[(b * 8 + d) * 128 + t] + pkv, 0.f) * wv;
        v += __shfl_down(v, 32); v += __shfl_down(v, 16); v += __shfl_down(v, 8);
        v += __shfl_down(v, 4);  v += __shfl_down(v, 2);  v += __shfl_down(v, 1);
        if (lane == 0) red[wid][d] = v;
    }
    __syncthreads();
    if (t < 8) out_ds[b * 400 + l * 8 + t] = red[0][t] + red[1][t];
}

// ---------------------------------------------------------------------------
// K7 (dominant): dsc[r, i] = sum_h relu(pd2[r,h] + pkcT[h,i]) * w_score[h]
// tile: 8 r x 256 i per block (256 threads); pd2 tile via LDS broadcast float4
__global__ __launch_bounds__(256) void k_cand_score(
    const float* __restrict__ ws_pd2, const float* __restrict__ ws_pkcT,
    const float* __restrict__ w_score, float* __restrict__ out_dsc)
{
    const int t = threadIdx.x;
    const int i = blockIdx.x * 256 + t;
    const int r0 = blockIdx.y * 8;
    __shared__ __align__(16) float pd_s[8 * 128];
    __shared__ __align__(16) float ws_s[128];
    for (int j = t; j < 8 * 128; j += 256) pd_s[j] = ws_pd2[r0 * 128 + j];
    if (t < 128) ws_s[t] = w_score[t];
    __syncthreads();
    float acc[8];
    #pragma unroll
    for (int r = 0; r < 8; ++r) acc[r] = 0.f;
    for (int h = 0; h < 128; h += 4) {
        const float pv0 = ws_pkcT[(size_t)(h + 0) * NI + i];
        const float pv1 = ws_pkcT[(size_t)(h + 1) * NI + i];
        const float pv2 = ws_pkcT[(size_t)(h + 2) * NI + i];
        const float pv3 = ws_pkcT[(size_t)(h + 3) * NI + i];
        const float4 w4 = *reinterpret_cast<const float4*>(&ws_s[h]);
        #pragma unroll
        for (int r = 0; r < 8; ++r) {
            const float4 p4 = *reinterpret_cast<const float4*>(&pd_s[r * 128 + h]);
            acc[r] = fmaf(fmaxf(p4.x + pv0, 0.f), w4.x, acc[r]);
            acc[r] = fmaf(fmaxf(p4.y + pv1, 0.f), w4.y, acc[r]);
            acc[r] = fmaf(fmaxf(p4.z + pv2, 0.f), w4.z, acc[r]);
            acc[r] = fmaf(fmaxf(p4.w + pv3, 0.f), w4.w, acc[r]);
        }
    }
    #pragma unroll
    for (int r = 0; r < 8; ++r) out_dsc[(size_t)(r0 + r) * NI + i] = acc[r];
}

// ---------------------------------------------------------------------------
extern "C" void kernel_launch(void* const* d_in, const int* in_sizes, int n_in,
                              void* d_out, int out_size, void* d_ws, size_t ws_size,
                              hipStream_t stream)
{
    const int*   input     = (const int*)d_in[0];
    const int*   cand      = (const int*)d_in[1];
    // d_in[2] session_last_catgy_index: unused by reference
    // d_in[3] mask_catgy: unused by reference
    const float* emb_table = (const float*)d_in[4];
    const float* Wd        = (const float*)d_in[5];
    const float* Wk        = (const float*)d_in[6];
    const float* bk        = (const float*)d_in[7];
    const float* W1        = (const float*)d_in[8];
    const float* b1        = (const float*)d_in[9];
    const float* w_score   = (const float*)d_in[10];
    const float* Wc        = (const float*)d_in[11];
    const float* bc        = (const float*)d_in[12];

    float* out = (float*)d_out;
    float* out_cat  = out + OFF_CAT;
    float* out_ds   = out + OFF_DS;
    float* out_dsc  = out + OFF_DSC;
    float* out_emb  = out + OFF_EMB;
    float* out_embc = out + OFF_EMBC;
    float* out_loss = out + OFF_LOSS;

    float* ws      = (float*)d_ws;
    float* ws_agg  = ws + WS_AGG;
    float* ws_pd2  = ws + WS_PD2;
    float* ws_pk   = ws + WS_PK;
    float* ws_pkcT = ws + WS_PKCT;

    k_session<<<200, 128, 0, stream>>>(input, emb_table, Wk, bk, W1, out_emb, ws_pk);
    k_cand<<<512, 128, 0, stream>>>(cand, emb_table, Wk, bk, W1, out_embc, ws_pkcT);
    k_agg<<<128, 256, 0, stream>>>(out_emb, Wd, ws_agg);
    k_pd2<<<128, 128, 0, stream>>>(ws_agg, W1, b1, ws_pd2);
    k_loss<<<1, 128, 0, stream>>>(ws_agg, out_loss);
    k_catgy<<<dim3(128, 8), 128, 0, stream>>>(ws_agg, Wc, bc, out_cat);
    k_demand_score<<<800, 128, 0, stream>>>(ws_pd2, ws_pk, w_score, out_ds);
    k_cand_score<<<dim3(32, 16), 256, 0, stream>>>(ws_pd2, ws_pkcT, w_score, out_dsc);
}

// Round 2
// 185.937 us; speedup vs baseline: 1.1928x; 1.1928x over previous
//
#include <hip/hip_runtime.h>
#include <hip/hip_bf16.h>

// Problem constants
// B=16, L=50, D=8, H=128, E=128, NC=1000, NI=8192
#define NB 16
#define NL 50
#define ND 8
#define NH 128
#define NC 1000
#define NI 8192

// Output flat offsets (return order): catgy(16*8*1000), demand_score(16*50*8 flat),
// demand_score_candidate(16*8*8192), emb(800*128), emb_cand(8192*128), loss(1)
#define OFF_CAT  0
#define OFF_DS   128000
#define OFF_DSC  134400
#define OFF_EMB  1182976
#define OFF_EMBC 1285376
#define OFF_LOSS 2333952

// Workspace layout (floats)
#define WS_AGG  0         // 16*8*128   = 16384
#define WS_PD2  16384     // 16*8*128   = 16384
#define WS_PK   32768     // 800*128    = 102400
#define WS_PKCT 135168    // 128*8192   = 1048576 (transposed [h][i])

// ---------------------------------------------------------------------------
// K1a: session rows — gather emb (write out), hk = emb@Wk+bk, pk = hk@Wk1 -> ws
// 4 rows per block, 128 threads (thread = output column). Block 0 also zeroes
// the loss accumulator (stream-ordered before k_loss's atomicAdd).
__global__ __launch_bounds__(128) void k_session(
    const int* __restrict__ inp, const float* __restrict__ emb_table,
    const float* __restrict__ Wk, const float* __restrict__ bk,
    const float* __restrict__ W1, float* __restrict__ out_emb,
    float* __restrict__ ws_pk, float* __restrict__ out_loss)
{
    const int t = threadIdx.x;
    const int row0 = blockIdx.x * 4;
    if (blockIdx.x == 0 && t == 0) out_loss[0] = 0.f;
    __shared__ __align__(16) float e_s[4][128];
    __shared__ __align__(16) float h_s[4][128];
    #pragma unroll
    for (int r = 0; r < 4; ++r) {
        const int cat = inp[row0 + r];
        const float v = emb_table[cat * 128 + t];
        e_s[r][t] = v;
        out_emb[(row0 + r) * 128 + t] = v;
    }
    __syncthreads();
    const float bkv = bk[t];
    float acc[4] = {bkv, bkv, bkv, bkv};
    for (int k = 0; k < 128; k += 4) {
        const float w0 = Wk[(k + 0) * 128 + t], w1 = Wk[(k + 1) * 128 + t];
        const float w2 = Wk[(k + 2) * 128 + t], w3 = Wk[(k + 3) * 128 + t];
        #pragma unroll
        for (int r = 0; r < 4; ++r) {
            const float4 e4 = *reinterpret_cast<const float4*>(&e_s[r][k]);
            acc[r] = fmaf(e4.w, w3, fmaf(e4.z, w2, fmaf(e4.y, w1, fmaf(e4.x, w0, acc[r]))));
        }
    }
    #pragma unroll
    for (int r = 0; r < 4; ++r) h_s[r][t] = acc[r];
    __syncthreads();
    const float* __restrict__ Wk1 = W1 + 128 * 128;
    float pk[4] = {0.f, 0.f, 0.f, 0.f};
    for (int k = 0; k < 128; k += 4) {
        const float w0 = Wk1[(k + 0) * 128 + t], w1 = Wk1[(k + 1) * 128 + t];
        const float w2 = Wk1[(k + 2) * 128 + t], w3 = Wk1[(k + 3) * 128 + t];
        #pragma unroll
        for (int r = 0; r < 4; ++r) {
            const float4 h4 = *reinterpret_cast<const float4*>(&h_s[r][k]);
            pk[r] = fmaf(h4.w, w3, fmaf(h4.z, w2, fmaf(h4.y, w1, fmaf(h4.x, w0, pk[r]))));
        }
    }
    #pragma unroll
    for (int r = 0; r < 4; ++r) ws_pk[(row0 + r) * 128 + t] = pk[r];
}

// ---------------------------------------------------------------------------
// K1b: candidate rows — gather emb_cand (write out), hk=emb@Wk+bk, pkc=hk@Wk1
// stored TRANSPOSED [h][i]. 16 rows per block, 128 threads.
__global__ __launch_bounds__(128) void k_cand(
    const int* __restrict__ cand, const float* __restrict__ emb_table,
    const float* __restrict__ Wk, const float* __restrict__ bk,
    const float* __restrict__ W1, float* __restrict__ out_embc,
    float* __restrict__ ws_pkcT)
{
    const int t = threadIdx.x;
    const int i0 = blockIdx.x * 16;
    __shared__ __align__(16) float e_s[16][128];
    __shared__ __align__(16) float h_s[16][128];
    #pragma unroll
    for (int r = 0; r < 16; ++r) {
        const int cat = cand[i0 + r];
        const float v = emb_table[cat * 128 + t];
        e_s[r][t] = v;
        out_embc[(i0 + r) * 128 + t] = v;
    }
    __syncthreads();
    const float bkv = bk[t];
    float acc[16];
    #pragma unroll
    for (int r = 0; r < 16; ++r) acc[r] = bkv;
    for (int k = 0; k < 128; k += 4) {
        const float w0 = Wk[(k + 0) * 128 + t], w1 = Wk[(k + 1) * 128 + t];
        const float w2 = Wk[(k + 2) * 128 + t], w3 = Wk[(k + 3) * 128 + t];
        #pragma unroll
        for (int r = 0; r < 16; ++r) {
            const float4 e4 = *reinterpret_cast<const float4*>(&e_s[r][k]);
            acc[r] = fmaf(e4.w, w3, fmaf(e4.z, w2, fmaf(e4.y, w1, fmaf(e4.x, w0, acc[r]))));
        }
    }
    #pragma unroll
    for (int r = 0; r < 16; ++r) h_s[r][t] = acc[r];
    __syncthreads();
    const float* __restrict__ Wk1 = W1 + 128 * 128;
    #pragma unroll
    for (int r = 0; r < 16; ++r) acc[r] = 0.f;
    for (int k = 0; k < 128; k += 4) {
        const float w0 = Wk1[(k + 0) * 128 + t], w1 = Wk1[(k + 1) * 128 + t];
        const float w2 = Wk1[(k + 2) * 128 + t], w3 = Wk1[(k + 3) * 128 + t];
        #pragma unroll
        for (int r = 0; r < 16; ++r) {
            const float4 h4 = *reinterpret_cast<const float4*>(&h_s[r][k]);
            acc[r] = fmaf(h4.w, w3, fmaf(h4.z, w2, fmaf(h4.y, w1, fmaf(h4.x, w0, acc[r]))));
        }
    }
    // per-thread 16 consecutive i's -> 4x float4 stores (64B/lane, line-granular)
    float4* dst = reinterpret_cast<float4*>(&ws_pkcT[(size_t)t * NI + i0]);
    #pragma unroll
    for (int r4 = 0; r4 < 4; ++r4)
        dst[r4] = make_float4(acc[r4 * 4 + 0], acc[r4 * 4 + 1], acc[r4 * 4 + 2], acc[r4 * 4 + 3]);
}

// ---------------------------------------------------------------------------
// K2 (fused): per block bd = b*8+d
//   agg[bd,:]   = logsumexp_l( emb[b,l,:] @ Wd[:, d*128+:] )      (256 thr)
//   pd2[bd,:]   = agg[bd,:] @ Wd1 + b1                            (128 thr)
//   catgy[bd,:] = agg[bd,:] @ Wc + bc                             (256 thr, 4 cols ea)
__global__ __launch_bounds__(256) void k_agg_fused(
    const float* __restrict__ out_emb, const float* __restrict__ Wd,
    const float* __restrict__ W1, const float* __restrict__ b1,
    const float* __restrict__ Wc, const float* __restrict__ bc,
    float* __restrict__ ws_agg, float* __restrict__ ws_pd2,
    float* __restrict__ out_cat)
{
    const int bd = blockIdx.x;         // b*8+d
    const int b = bd >> 3, d = bd & 7;
    const int t = threadIdx.x;
    const int c = t & 127, half = t >> 7;
    __shared__ __align__(16) float e_s[NL * 128];
    __shared__ __align__(16) float a_s[128];
    __shared__ float m_s[2][128];
    __shared__ float s_s[2][128];
    for (int i = t; i < NL * 128; i += 256) e_s[i] = out_emb[b * NL * 128 + i];
    __syncthreads();
    const float* __restrict__ wp = Wd + d * 128 + c;
    float hd[25];
    #pragma unroll
    for (int l = 0; l < 25; ++l) hd[l] = 0.f;
    const int l0 = half * 25;
    for (int k = 0; k < 128; k += 4) {
        const float w0 = wp[(k + 0) * 1024], w1 = wp[(k + 1) * 1024];
        const float w2 = wp[(k + 2) * 1024], w3 = wp[(k + 3) * 1024];
        #pragma unroll
        for (int l = 0; l < 25; ++l) {
            const float4 e4 = *reinterpret_cast<const float4*>(&e_s[(l0 + l) * 128 + k]);
            hd[l] = fmaf(e4.w, w3, fmaf(e4.z, w2, fmaf(e4.y, w1, fmaf(e4.x, w0, hd[l]))));
        }
    }
    float m = hd[0];
    #pragma unroll
    for (int l = 1; l < 25; ++l) m = fmaxf(m, hd[l]);
    float s = 0.f;
    #pragma unroll
    for (int l = 0; l < 25; ++l) s += expf(hd[l] - m);
    m_s[half][c] = m; s_s[half][c] = s;
    __syncthreads();
    if (half == 0) {
        const float m0 = m_s[0][c], m1 = m_s[1][c];
        const float M = fmaxf(m0, m1);
        const float sv = s_s[0][c] * expf(m0 - M) + s_s[1][c] * expf(m1 - M);
        const float av = M + logf(sv);
        a_s[c] = av;
        ws_agg[bd * 128 + c] = av;
    }
    __syncthreads();
    // ---- pd2 = agg @ Wd1 + b1 (Wd1 = first 128 rows of W1) ----
    if (half == 0) {
        float acc = b1[c];
        for (int k = 0; k < 128; k += 4) {
            acc = fmaf(a_s[k + 0], W1[(k + 0) * 128 + c], acc);
            acc = fmaf(a_s[k + 1], W1[(k + 1) * 128 + c], acc);
            acc = fmaf(a_s[k + 2], W1[(k + 2) * 128 + c], acc);
            acc = fmaf(a_s[k + 3], W1[(k + 3) * 128 + c], acc);
        }
        ws_pd2[bd * 128 + c] = acc;
    }
    // ---- catgy = agg @ Wc + bc: 256 threads x 4 cols each ----
    float acc4[4];
    int   col4[4];
    #pragma unroll
    for (int j = 0; j < 4; ++j) {
        const int col = t + j * 256;
        col4[j] = (col < NC) ? col : (NC - 1);       // safe index, store guarded
        acc4[j] = bc[col4[j]];
    }
    for (int k = 0; k < 128; ++k) {
        const float av = a_s[k];
        const float* wr = Wc + (size_t)k * NC;
        #pragma unroll
        for (int j = 0; j < 4; ++j) acc4[j] = fmaf(av, wr[col4[j]], acc4[j]);
    }
    #pragma unroll
    for (int j = 0; j < 4; ++j) {
        const int col = t + j * 256;
        if (col < NC) out_cat[bd * NC + col] = acc4[j];
    }
}

// ---------------------------------------------------------------------------
// K3: demand_sim_loss — one block per b (16 blocks), atomicAdd into scalar.
// loss_b = sum_h S_h^2 - sum_d nsq_d * inv_d^2   (exact diagonal identity)
__global__ __launch_bounds__(128) void k_loss(
    const float* __restrict__ agg, float* __restrict__ out_loss)
{
    const int b = blockIdx.x;
    const int t = threadIdx.x;
    const int lane = t & 63, wid = t >> 6;
    __shared__ float normp[2][8];
    __shared__ float wred[2];
    float a[8];
    #pragma unroll
    for (int d = 0; d < 8; ++d) a[d] = agg[(b * 8 + d) * 128 + t];
    #pragma unroll
    for (int d = 0; d < 8; ++d) {
        float s = a[d] * a[d];
        s += __shfl_down(s, 32); s += __shfl_down(s, 16); s += __shfl_down(s, 8);
        s += __shfl_down(s, 4);  s += __shfl_down(s, 2);  s += __shfl_down(s, 1);
        if (lane == 0) normp[wid][d] = s;
    }
    __syncthreads();
    float corr = 0.f, S = 0.f;
    #pragma unroll
    for (int d = 0; d < 8; ++d) {
        const float nsq = normp[0][d] + normp[1][d];
        const float iv = 1.f / (sqrtf(nsq) + 1e-12f);
        corr = fmaf(nsq, iv * iv, corr);
        S = fmaf(a[d], iv, S);
    }
    float p = S * S;
    p += __shfl_down(p, 32); p += __shfl_down(p, 16); p += __shfl_down(p, 8);
    p += __shfl_down(p, 4);  p += __shfl_down(p, 2);  p += __shfl_down(p, 1);
    if (lane == 0) wred[wid] = p;
    __syncthreads();
    if (t == 0)
        atomicAdd(out_loss, (wred[0] + wred[1] - corr) * (1.0f / 896.0f));
}

// ---------------------------------------------------------------------------
// K4: demand_score[b,l,d] = sum_h relu(pd2[b,d,h]+pk[b,l,h]) * w_score[h]
// Flat output index b*400 + l*8 + d (the (B,L,D)->(B,D,L) reshape is flat-identity)
__global__ __launch_bounds__(128) void k_demand_score(
    const float* __restrict__ ws_pd2, const float* __restrict__ ws_pk,
    const float* __restrict__ w_score, float* __restrict__ out_ds)
{
    const int bl = blockIdx.x;         // b*50+l
    const int b = bl / 50, l = bl % 50;
    const int t = threadIdx.x;
    __shared__ float red[2][8];
    const int lane = t & 63, wid = t >> 6;
    const float pkv = ws_pk[bl * 128 + t];
    const float wv = w_score[t];
    #pragma unroll
    for (int d = 0; d < 8; ++d) {
        float v = fmaxf(ws_pd2[(b * 8 + d) * 128 + t] + pkv, 0.f) * wv;
        v += __shfl_down(v, 32); v += __shfl_down(v, 16); v += __shfl_down(v, 8);
        v += __shfl_down(v, 4);  v += __shfl_down(v, 2);  v += __shfl_down(v, 1);
        if (lane == 0) red[wid][d] = v;
    }
    __syncthreads();
    if (t < 8) out_ds[b * 400 + l * 8 + t] = red[0][t] + red[1][t];
}

// ---------------------------------------------------------------------------
// K5 (dominant): dsc[r, i] = sum_h relu(pd2[r,h] + pkcT[h,i]) * w_score[h]
// tile: 8 r x 256 i per block (256 threads); pd2 tile via LDS broadcast float4
__global__ __launch_bounds__(256) void k_cand_score(
    const float* __restrict__ ws_pd2, const float* __restrict__ ws_pkcT,
    const float* __restrict__ w_score, float* __restrict__ out_dsc)
{
    const int t = threadIdx.x;
    const int i = blockIdx.x * 256 + t;
    const int r0 = blockIdx.y * 8;
    __shared__ __align__(16) float pd_s[8 * 128];
    __shared__ __align__(16) float ws_s[128];
    for (int j = t; j < 8 * 128; j += 256) pd_s[j] = ws_pd2[r0 * 128 + j];
    if (t < 128) ws_s[t] = w_score[t];
    __syncthreads();
    float acc[8];
    #pragma unroll
    for (int r = 0; r < 8; ++r) acc[r] = 0.f;
    for (int h = 0; h < 128; h += 4) {
        const float pv0 = ws_pkcT[(size_t)(h + 0) * NI + i];
        const float pv1 = ws_pkcT[(size_t)(h + 1) * NI + i];
        const float pv2 = ws_pkcT[(size_t)(h + 2) * NI + i];
        const float pv3 = ws_pkcT[(size_t)(h + 3) * NI + i];
        const float4 w4 = *reinterpret_cast<const float4*>(&ws_s[h]);
        #pragma unroll
        for (int r = 0; r < 8; ++r) {
            const float4 p4 = *reinterpret_cast<const float4*>(&pd_s[r * 128 + h]);
            acc[r] = fmaf(fmaxf(p4.x + pv0, 0.f), w4.x, acc[r]);
            acc[r] = fmaf(fmaxf(p4.y + pv1, 0.f), w4.y, acc[r]);
            acc[r] = fmaf(fmaxf(p4.z + pv2, 0.f), w4.z, acc[r]);
            acc[r] = fmaf(fmaxf(p4.w + pv3, 0.f), w4.w, acc[r]);
        }
    }
    #pragma unroll
    for (int r = 0; r < 8; ++r) out_dsc[(size_t)(r0 + r) * NI + i] = acc[r];
}

// ---------------------------------------------------------------------------
extern "C" void kernel_launch(void* const* d_in, const int* in_sizes, int n_in,
                              void* d_out, int out_size, void* d_ws, size_t ws_size,
                              hipStream_t stream)
{
    const int*   input     = (const int*)d_in[0];
    const int*   cand      = (const int*)d_in[1];
    // d_in[2] session_last_catgy_index: unused by reference
    // d_in[3] mask_catgy: unused by reference
    const float* emb_table = (const float*)d_in[4];
    const float* Wd        = (const float*)d_in[5];
    const float* Wk        = (const float*)d_in[6];
    const float* bk        = (const float*)d_in[7];
    const float* W1        = (const float*)d_in[8];
    const float* b1        = (const float*)d_in[9];
    const float* w_score   = (const float*)d_in[10];
    const float* Wc        = (const float*)d_in[11];
    const float* bc        = (const float*)d_in[12];

    float* out = (float*)d_out;
    float* out_cat  = out + OFF_CAT;
    float* out_ds   = out + OFF_DS;
    float* out_dsc  = out + OFF_DSC;
    float* out_emb  = out + OFF_EMB;
    float* out_embc = out + OFF_EMBC;
    float* out_loss = out + OFF_LOSS;

    float* ws      = (float*)d_ws;
    float* ws_agg  = ws + WS_AGG;
    float* ws_pd2  = ws + WS_PD2;
    float* ws_pk   = ws + WS_PK;
    float* ws_pkcT = ws + WS_PKCT;

    k_session<<<200, 128, 0, stream>>>(input, emb_table, Wk, bk, W1, out_emb, ws_pk, out_loss);
    k_cand<<<512, 128, 0, stream>>>(cand, emb_table, Wk, bk, W1, out_embc, ws_pkcT);
    k_agg_fused<<<128, 256, 0, stream>>>(out_emb, Wd, W1, b1, Wc, bc, ws_agg, ws_pd2, out_cat);
    k_loss<<<16, 128, 0, stream>>>(ws_agg, out_loss);
    k_demand_score<<<800, 128, 0, stream>>>(ws_pd2, ws_pk, w_score, out_ds);
    k_cand_score<<<dim3(32, 16), 256, 0, stream>>>(ws_pd2, ws_pkcT, w_score, out_dsc);
}

// Round 3
// 140.043 us; speedup vs baseline: 1.5837x; 1.3277x over previous
//
#include <hip/hip_runtime.h>
#include <hip/hip_bf16.h>

// Problem constants: B=16, L=50, D=8, H=128, E=128, NC=1000, NI=8192
#define NB 16
#define NL 50
#define ND 8
#define NH 128
#define NC 1000
#define NI 8192

// Output flat offsets (return order)
#define OFF_CAT  0
#define OFF_DS   128000
#define OFF_DSC  134400
#define OFF_EMB  1182976
#define OFF_EMBC 1285376
#define OFF_LOSS 2333952

// Workspace layout (floats)
#define WS_AGG   0          // 16*8*128      = 16384
#define WS_PD2   16384      // 16*8*128      = 16384
#define WS_PK    32768      // 800*128       = 102400
#define WS_SPART 135168     // 128*5*128     = 81920 (sum-exp partials per l-chunk)
#define WS_PKCT  217088     // 128*8192      = 1048576 (transposed [h][i])
// total = 1265664 floats = 5.06 MB

// ---------------------------------------------------------------------------
// Level 1 (one launch): blocks 0..99 session rows (8/block), 100..611 cand
// rows (16/block). 256 threads: c = t&127 (column), g = t>>7 (row group).
__global__ __launch_bounds__(256) void k_embed(
    const int* __restrict__ inp, const int* __restrict__ cand,
    const float* __restrict__ emb_table, const float* __restrict__ Wk,
    const float* __restrict__ bk, const float* __restrict__ W1,
    float* __restrict__ out_emb, float* __restrict__ out_embc,
    float* __restrict__ ws_pk, float* __restrict__ ws_pkcT,
    float* __restrict__ out_loss)
{
    const int t = threadIdx.x;
    const int c = t & 127, g = t >> 7;
    __shared__ __align__(16) float smem[4096];   // s_e = smem[0..2047], s_h = smem[2048..4095]
    float* s_e = smem;
    float* s_h = smem + 2048;
    const float* __restrict__ Wk1 = W1 + 128 * 128;
    const float bkv = bk[c];

    if (blockIdx.x < 100) {
        // ---- session: 8 rows, group g handles rows g*4..g*4+3 ----
        if (blockIdx.x == 0 && t == 0) out_loss[0] = 0.f;
        const int r0 = blockIdx.x * 8;
        #pragma unroll
        for (int r = 0; r < 4; ++r) {
            const int gr = g * 4 + r;
            const int cat = inp[r0 + gr];
            const float v = emb_table[cat * 128 + c];
            s_e[gr * 128 + c] = v;
            out_emb[(r0 + gr) * 128 + c] = v;
        }
        __syncthreads();
        float acc[4] = {bkv, bkv, bkv, bkv};
        for (int k = 0; k < 128; k += 4) {
            const float w0 = Wk[(k + 0) * 128 + c], w1 = Wk[(k + 1) * 128 + c];
            const float w2 = Wk[(k + 2) * 128 + c], w3 = Wk[(k + 3) * 128 + c];
            #pragma unroll
            for (int r = 0; r < 4; ++r) {
                const float4 e4 = *reinterpret_cast<const float4*>(&s_e[(g * 4 + r) * 128 + k]);
                acc[r] = fmaf(e4.w, w3, fmaf(e4.z, w2, fmaf(e4.y, w1, fmaf(e4.x, w0, acc[r]))));
            }
        }
        #pragma unroll
        for (int r = 0; r < 4; ++r) s_h[(g * 4 + r) * 128 + c] = acc[r];
        __syncthreads();
        float pk[4] = {0.f, 0.f, 0.f, 0.f};
        for (int k = 0; k < 128; k += 4) {
            const float w0 = Wk1[(k + 0) * 128 + c], w1 = Wk1[(k + 1) * 128 + c];
            const float w2 = Wk1[(k + 2) * 128 + c], w3 = Wk1[(k + 3) * 128 + c];
            #pragma unroll
            for (int r = 0; r < 4; ++r) {
                const float4 h4 = *reinterpret_cast<const float4*>(&s_h[(g * 4 + r) * 128 + k]);
                pk[r] = fmaf(h4.w, w3, fmaf(h4.z, w2, fmaf(h4.y, w1, fmaf(h4.x, w0, pk[r]))));
            }
        }
        #pragma unroll
        for (int r = 0; r < 4; ++r) ws_pk[(r0 + g * 4 + r) * 128 + c] = pk[r];
    } else {
        // ---- candidates: 16 rows, group g handles rows g*8..g*8+7 ----
        const int i0 = (blockIdx.x - 100) * 16;
        #pragma unroll
        for (int r = 0; r < 8; ++r) {
            const int gr = g * 8 + r;
            const int cat = cand[i0 + gr];
            const float v = emb_table[cat * 128 + c];
            s_e[gr * 128 + c] = v;
            out_embc[(i0 + gr) * 128 + c] = v;
        }
        __syncthreads();
        float acc[8];
        #pragma unroll
        for (int r = 0; r < 8; ++r) acc[r] = bkv;
        for (int k = 0; k < 128; k += 4) {
            const float w0 = Wk[(k + 0) * 128 + c], w1 = Wk[(k + 1) * 128 + c];
            const float w2 = Wk[(k + 2) * 128 + c], w3 = Wk[(k + 3) * 128 + c];
            #pragma unroll
            for (int r = 0; r < 8; ++r) {
                const float4 e4 = *reinterpret_cast<const float4*>(&s_e[(g * 8 + r) * 128 + k]);
                acc[r] = fmaf(e4.w, w3, fmaf(e4.z, w2, fmaf(e4.y, w1, fmaf(e4.x, w0, acc[r]))));
            }
        }
        #pragma unroll
        for (int r = 0; r < 8; ++r) s_h[(g * 8 + r) * 128 + c] = acc[r];
        __syncthreads();
        #pragma unroll
        for (int r = 0; r < 8; ++r) acc[r] = 0.f;
        for (int k = 0; k < 128; k += 4) {
            const float w0 = Wk1[(k + 0) * 128 + c], w1 = Wk1[(k + 1) * 128 + c];
            const float w2 = Wk1[(k + 2) * 128 + c], w3 = Wk1[(k + 3) * 128 + c];
            #pragma unroll
            for (int r = 0; r < 8; ++r) {
                const float4 h4 = *reinterpret_cast<const float4*>(&s_h[(g * 8 + r) * 128 + k]);
                acc[r] = fmaf(h4.w, w3, fmaf(h4.z, w2, fmaf(h4.y, w1, fmaf(h4.x, w0, acc[r]))));
            }
        }
        // LDS transpose: tb[i_local][h] with stride 132 (conflict-free writes),
        // then 64B-contiguous global stores (4 lanes cover 64B per instr).
        __syncthreads();                       // all GEMV reads of smem done
        float* tb = smem;                      // 16*132 = 2112 floats
        #pragma unroll
        for (int r = 0; r < 8; ++r) tb[(g * 8 + r) * 132 + c] = acc[r];
        __syncthreads();
        #pragma unroll
        for (int p = 0; p < 2; ++p) {
            const int h = p * 64 + (t >> 2);
            const int ib = (t & 3) * 4;
            const float4 v = make_float4(tb[(ib + 0) * 132 + h], tb[(ib + 1) * 132 + h],
                                         tb[(ib + 2) * 132 + h], tb[(ib + 3) * 132 + h]);
            *reinterpret_cast<float4*>(&ws_pkcT[(size_t)h * NI + i0 + ib]) = v;
        }
    }
}

// ---------------------------------------------------------------------------
// Level 2: partial sum-exp over l-chunks. Block = (bd, chunk) -> 640 blocks.
// Spart[bd][chunk][h] = sum_{l in chunk} exp( emb[b,l,:] @ Wd[:, d*128+h] )
// (max-free LSE: |hd| <= ~0.25, exp is safe; diff vs max-shifted is rounding)
__global__ __launch_bounds__(256) void k_dsum(
    const float* __restrict__ out_emb, const float* __restrict__ Wd,
    float* __restrict__ ws_spart)
{
    const int bx = blockIdx.x;
    const int bd = bx / 5, chunk = bx % 5;
    const int b = bd >> 3, d = bd & 7;
    const int t = threadIdx.x;
    const int c = t & 127, half = t >> 7;
    __shared__ __align__(16) float se[1280];
    __shared__ float ss[2][128];
    const float* __restrict__ src = out_emb + (b * NL + chunk * 10) * 128;
    for (int i = t; i < 1280; i += 256) se[i] = src[i];
    __syncthreads();
    const float* __restrict__ wp = Wd + d * 128 + c;
    float acc[5] = {0.f, 0.f, 0.f, 0.f, 0.f};
    const int l0 = half * 5;
    for (int k = 0; k < 128; k += 4) {
        const float w0 = wp[(k + 0) * 1024], w1 = wp[(k + 1) * 1024];
        const float w2 = wp[(k + 2) * 1024], w3 = wp[(k + 3) * 1024];
        #pragma unroll
        for (int li = 0; li < 5; ++li) {
            const float4 e4 = *reinterpret_cast<const float4*>(&se[(l0 + li) * 128 + k]);
            acc[li] = fmaf(e4.w, w3, fmaf(e4.z, w2, fmaf(e4.y, w1, fmaf(e4.x, w0, acc[li]))));
        }
    }
    float s = 0.f;
    #pragma unroll
    for (int li = 0; li < 5; ++li) s += expf(acc[li]);
    ss[half][c] = s;
    __syncthreads();
    if (half == 0)
        ws_spart[(bd * 5 + chunk) * 128 + c] = ss[0][c] + ss[1][c];
}

// ---------------------------------------------------------------------------
// Level 3: agg = log(sum of partials); then pd2 = agg@Wd1+b1 and
// catgy = agg@Wc+bc fused (block per bd = 128 blocks, 256 threads)
__global__ __launch_bounds__(256) void k_agg2(
    const float* __restrict__ ws_spart, const float* __restrict__ W1,
    const float* __restrict__ b1, const float* __restrict__ Wc,
    const float* __restrict__ bc, float* __restrict__ ws_agg,
    float* __restrict__ ws_pd2, float* __restrict__ out_cat)
{
    const int bd = blockIdx.x;
    const int t = threadIdx.x;
    const int c = t & 127, half = t >> 7;
    __shared__ __align__(16) float a_s[128];
    if (half == 0) {
        float s = 0.f;
        #pragma unroll
        for (int ch = 0; ch < 5; ++ch) s += ws_spart[(bd * 5 + ch) * 128 + c];
        const float av = logf(s);
        a_s[c] = av;
        ws_agg[bd * 128 + c] = av;
    }
    __syncthreads();
    if (half == 0) {
        float acc = b1[c];
        for (int k = 0; k < 128; k += 4) {
            acc = fmaf(a_s[k + 0], W1[(k + 0) * 128 + c], acc);
            acc = fmaf(a_s[k + 1], W1[(k + 1) * 128 + c], acc);
            acc = fmaf(a_s[k + 2], W1[(k + 2) * 128 + c], acc);
            acc = fmaf(a_s[k + 3], W1[(k + 3) * 128 + c], acc);
        }
        ws_pd2[bd * 128 + c] = acc;
    }
    float acc4[4];
    int   col4[4];
    #pragma unroll
    for (int j = 0; j < 4; ++j) {
        const int col = t + j * 256;
        col4[j] = (col < NC) ? col : (NC - 1);
        acc4[j] = bc[col4[j]];
    }
    for (int k = 0; k < 128; ++k) {
        const float av = a_s[k];
        const float* wr = Wc + (size_t)k * NC;
        #pragma unroll
        for (int j = 0; j < 4; ++j) acc4[j] = fmaf(av, wr[col4[j]], acc4[j]);
    }
    #pragma unroll
    for (int j = 0; j < 4; ++j) {
        const int col = t + j * 256;
        if (col < NC) out_cat[bd * NC + col] = acc4[j];
    }
}

// ---------------------------------------------------------------------------
// Level 4 (one launch, 256 threads): blocks 0..511 cand_score,
// 512..1311 demand_score (one (b,l) each), 1312..1327 loss (one b each)
__global__ __launch_bounds__(256) void k_scores(
    const float* __restrict__ ws_pd2, const float* __restrict__ ws_pkcT,
    const float* __restrict__ ws_pk, const float* __restrict__ ws_agg,
    const float* __restrict__ w_score, float* __restrict__ out_dsc,
    float* __restrict__ out_ds, float* __restrict__ out_loss)
{
    const int bx = blockIdx.x;
    const int t = threadIdx.x;
    __shared__ __align__(16) float pd_s[1024];
    __shared__ __align__(16) float aux[276];   // ws_s / red / normp+sp+wred

    if (bx < 512) {
        // ---- cand_score: dsc[r,i] = sum_h relu(pd2[r,h]+pkcT[h,i])*w[h] ----
        const int i = (bx & 31) * 256 + t;
        const int r0 = (bx >> 5) * 8;
        for (int j = t; j < 8 * 128; j += 256) pd_s[j] = ws_pd2[r0 * 128 + j];
        if (t < 128) aux[t] = w_score[t];
        __syncthreads();
        float acc[8];
        #pragma unroll
        for (int r = 0; r < 8; ++r) acc[r] = 0.f;
        for (int h = 0; h < 128; h += 4) {
            const float pv0 = ws_pkcT[(size_t)(h + 0) * NI + i];
            const float pv1 = ws_pkcT[(size_t)(h + 1) * NI + i];
            const float pv2 = ws_pkcT[(size_t)(h + 2) * NI + i];
            const float pv3 = ws_pkcT[(size_t)(h + 3) * NI + i];
            const float4 w4 = *reinterpret_cast<const float4*>(&aux[h]);
            #pragma unroll
            for (int r = 0; r < 8; ++r) {
                const float4 p4 = *reinterpret_cast<const float4*>(&pd_s[r * 128 + h]);
                acc[r] = fmaf(fmaxf(p4.x + pv0, 0.f), w4.x, acc[r]);
                acc[r] = fmaf(fmaxf(p4.y + pv1, 0.f), w4.y, acc[r]);
                acc[r] = fmaf(fmaxf(p4.z + pv2, 0.f), w4.z, acc[r]);
                acc[r] = fmaf(fmaxf(p4.w + pv3, 0.f), w4.w, acc[r]);
            }
        }
        #pragma unroll
        for (int r = 0; r < 8; ++r) out_dsc[(size_t)(r0 + r) * NI + i] = acc[r];
    } else if (bx < 1312) {
        // ---- demand_score: group g covers d = g*4..g*4+3 ----
        const int bl = bx - 512;
        const int b = bl / 50, l = bl % 50;
        const int c = t & 127, g = t >> 7;
        const int w = t >> 6, lane = t & 63;
        float* red = aux;                      // [4][4]
        const float pkv = ws_pk[bl * 128 + c];
        const float wv = w_score[c];
        #pragma unroll
        for (int r = 0; r < 4; ++r) {
            const int d = g * 4 + r;
            float v = fmaxf(ws_pd2[(b * 8 + d) * 128 + c] + pkv, 0.f) * wv;
            v += __shfl_down(v, 32); v += __shfl_down(v, 16); v += __shfl_down(v, 8);
            v += __shfl_down(v, 4);  v += __shfl_down(v, 2);  v += __shfl_down(v, 1);
            if (lane == 0) red[w * 4 + r] = v;
        }
        __syncthreads();
        if (t < 8) {
            const int gg = t >> 2, rr = t & 3;
            out_ds[b * 400 + l * 8 + t] = red[(2 * gg) * 4 + rr] + red[(2 * gg + 1) * 4 + rr];
        }
    } else {
        // ---- loss: block per b; loss_b = sum_h S_h^2 - sum_d nsq_d*iv_d^2 ----
        const int b = bx - 1312;
        const int c = t & 127, g = t >> 7;
        const int w = t >> 6, lane = t & 63;
        float* normp = aux;            // [4][4]
        float* sp    = aux + 16;       // [2][128]
        float* wred  = aux + 272;      // [4]
        float a[4];
        #pragma unroll
        for (int r = 0; r < 4; ++r) a[r] = ws_agg[(b * 8 + g * 4 + r) * 128 + c];
        #pragma unroll
        for (int r = 0; r < 4; ++r) {
            float s = a[r] * a[r];
            s += __shfl_down(s, 32); s += __shfl_down(s, 16); s += __shfl_down(s, 8);
            s += __shfl_down(s, 4);  s += __shfl_down(s, 2);  s += __shfl_down(s, 1);
            if (lane == 0) normp[w * 4 + r] = s;
        }
        __syncthreads();
        float Sp = 0.f;
        #pragma unroll
        for (int r = 0; r < 4; ++r) {
            const float nsq = normp[(2 * g) * 4 + r] + normp[(2 * g + 1) * 4 + r];
            const float iv = 1.f / (sqrtf(nsq) + 1e-12f);
            Sp = fmaf(a[r], iv, Sp);
        }
        sp[g * 128 + c] = Sp;
        __syncthreads();
        float p = 0.f;
        if (t < 128) {
            const float S = sp[c] + sp[128 + c];
            p = S * S;
        }
        p += __shfl_down(p, 32); p += __shfl_down(p, 16); p += __shfl_down(p, 8);
        p += __shfl_down(p, 4);  p += __shfl_down(p, 2);  p += __shfl_down(p, 1);
        if (lane == 0) wred[w] = p;
        __syncthreads();
        if (t == 0) {
            float corr = 0.f;
            #pragma unroll
            for (int d = 0; d < 8; ++d) {
                const float nsq = normp[(2 * (d >> 2)) * 4 + (d & 3)] +
                                  normp[(2 * (d >> 2) + 1) * 4 + (d & 3)];
                const float iv = 1.f / (sqrtf(nsq) + 1e-12f);
                corr = fmaf(nsq, iv * iv, corr);
            }
            atomicAdd(out_loss,
                      (wred[0] + wred[1] + wred[2] + wred[3] - corr) * (1.0f / 896.0f));
        }
    }
}

// ---------------------------------------------------------------------------
extern "C" void kernel_launch(void* const* d_in, const int* in_sizes, int n_in,
                              void* d_out, int out_size, void* d_ws, size_t ws_size,
                              hipStream_t stream)
{
    const int*   input     = (const int*)d_in[0];
    const int*   cand      = (const int*)d_in[1];
    const float* emb_table = (const float*)d_in[4];
    const float* Wd        = (const float*)d_in[5];
    const float* Wk        = (const float*)d_in[6];
    const float* bk        = (const float*)d_in[7];
    const float* W1        = (const float*)d_in[8];
    const float* b1        = (const float*)d_in[9];
    const float* w_score   = (const float*)d_in[10];
    const float* Wc        = (const float*)d_in[11];
    const float* bc        = (const float*)d_in[12];

    float* out = (float*)d_out;
    float* out_cat  = out + OFF_CAT;
    float* out_ds   = out + OFF_DS;
    float* out_dsc  = out + OFF_DSC;
    float* out_emb  = out + OFF_EMB;
    float* out_embc = out + OFF_EMBC;
    float* out_loss = out + OFF_LOSS;

    float* ws       = (float*)d_ws;
    float* ws_agg   = ws + WS_AGG;
    float* ws_pd2   = ws + WS_PD2;
    float* ws_pk    = ws + WS_PK;
    float* ws_spart = ws + WS_SPART;
    float* ws_pkcT  = ws + WS_PKCT;

    k_embed<<<612, 256, 0, stream>>>(input, cand, emb_table, Wk, bk, W1,
                                     out_emb, out_embc, ws_pk, ws_pkcT, out_loss);
    k_dsum<<<640, 256, 0, stream>>>(out_emb, Wd, ws_spart);
    k_agg2<<<128, 256, 0, stream>>>(ws_spart, W1, b1, Wc, bc, ws_agg, ws_pd2, out_cat);
    k_scores<<<1328, 256, 0, stream>>>(ws_pd2, ws_pkcT, ws_pk, ws_agg, w_score,
                                       out_dsc, out_ds, out_loss);
}